// Round 18
// baseline (221.666 us; speedup 1.0000x reference)
//
#include <hip/hip_runtime.h>

#define TT    2000
#define NG    4000
#define WARM  365
#define LENF  15
#define NPHY  12
#define BLK   40                  // timesteps per block (50 blocks, exact)
#define NBLK  50
#define STW   96                  // floats per step (32 cells * 3)
#define SLOT  (BLK * STW)         // 3840 floats per stage slot
#define PAIRS (BLK / 2)           // 20
#define ROWF  (3 * NG)            // floats per timestep row

typedef const float __attribute__((address_space(1)))* gptr_t;
typedef float __attribute__((address_space(3)))* lptr_t;
typedef __attribute__((ext_vector_type(2))) float f32x2;

// Quad-wide sum via DPP (VALU-only). All 4 lanes of a quad get the sum.
__device__ __forceinline__ float quad_sum(float x) {
    int a = __builtin_amdgcn_update_dpp(0, __float_as_int(x), 0xB1, 0xF, 0xF, true);
    float s = x + __int_as_float(a);
    int b = __builtin_amdgcn_update_dpp(0, __float_as_int(s), 0x4E, 0xF, 0xF, true);
    return s + __int_as_float(b);
}

#define WG_BARRIER() asm volatile("s_waitcnt lgkmcnt(0)\n\ts_barrier" ::: "memory")

// Kernel 1: serial region, ILP=2 per lane (each lane owns the chains of TWO
// grid cells: cellA = lane>>2, cellB = cellA+16; WG covers 32 cells, 125 WGs).
// r17 post-mortem: wall time = max stage span = soil chain's serial dependent
// latency (~176 cyc/step). Two independent chains per lane interleave in the
// issue slots -> effective latency per step ~halves. 3 waves:
//   wave0: staging(30 loads) + snow x2 -> s_rt ring
//   wave1: staging(30 loads) + soil x2 -> s_rex ring
//   wave2: response x2 + quad mean -> qm global (no stage loads -> no vmcnt
//          drain: its stores stay in flight across the barrier)
__global__ __launch_bounds__(192, 1) void hbv_chain_kernel(
    const float* __restrict__ xphy,   // [T, G, 3]
    const float* __restrict__ prm,    // [1, G, 50]
    float* __restrict__ qm)           // [T, G] workspace: quad-SUM of q
{
    __shared__ float s_stage[3 * SLOT];        // 46080 B, 3-slot ring
    __shared__ f32x2 s_rt [2 * PAIRS * 128];   // 40960 B
    __shared__ f32x2 s_rex[2 * PAIRS * 128];   // 40960 B

    const int lane  = threadIdx.x & 63;
    const int wid   = threadIdx.x >> 6;   // 0..2
    const int g0    = blockIdx.x * 32;    // 125 WGs * 32 cells
    const int cellA = lane >> 2;          // 0..15
    const int cellB = cellA + 16;
    const int m     = lane & 3;
    const int gA    = g0 + cellA;
    const int gB    = g0 + cellB;

    const float* pgA = prm + (size_t)gA * 50;
    const float* pgB = prm + (size_t)gB * 50;

    const float lb[NPHY] = {1.0f, 50.0f, 0.05f, 0.01f, 0.001f, 0.2f, 0.0f, 0.0f, -2.5f, 0.5f, 0.0f, 0.0f};
    const float ub[NPHY] = {6.0f, 1000.0f, 0.9f, 0.5f, 0.2f, 1.0f, 10.0f, 100.0f, 2.5f, 10.0f, 0.1f, 0.2f};
    float phA[NPHY], phB[NPHY];
    #pragma unroll
    for (int i = 0; i < NPHY; ++i) {
        phA[i] = lb[i] + pgA[i * 4 + m] * (ub[i] - lb[i]);
        phB[i] = lb[i] + pgB[i * 4 + m] * (ub[i] - lb[i]);
    }
    const float betaA = phA[0], fcA = phA[1], k0A = phA[2], k1A = phA[3], k2A = phA[4],
                lpA = phA[5], percA = phA[6], uzlA = phA[7], ttpA = phA[8],
                cfmaxA = phA[9], cwhA = phA[11];
    const float betaB = phB[0], fcB = phB[1], k0B = phB[2], k1B = phB[3], k2B = phB[4],
                lpB = phB[5], percB = phB[6], uzlB = phB[7], ttpB = phB[8],
                cfmaxB = phB[9], cwhB = phB[11];
    const float cfrcfA = phA[10] * cfmaxA, cfrcfB = phB[10] * cfmaxB;
    const float rlpfcA = 1.0f / (lpA * fcA), rlpfcB = 1.0f / (lpB * fcB);
    const float blfcA  = betaA * __builtin_amdgcn_logf(1.0f / fcA);
    const float blfcB  = betaB * __builtin_amdgcn_logf(1.0f / fcB);
    const float onemk1A = 1.0f - k1A, onemk1B = 1.0f - k1B;
    const float onemk2A = 1.0f - k2A, onemk2B = 1.0f - k2B;

    // Per-wave persistent states (x2 chains)
    float spA = 0.001f, mwA = 0.001f, spB = 0.001f, mwB = 0.001f;  // wave0
    float smA = 0.001f, smB = 0.001f;                               // wave1
    float suzA = 0.001f, slzA = 0.001f, suzB = 0.001f, slzB = 0.001f; // wave2

    // staging offsets (waves 0,1: 30 size-4 loads each; 60 x 64 lanes = 3840
    // dwords = one 40x96 block). flat dword -> (step, ofs-within-96).
    int doff[30];
    #pragma unroll
    for (int ld = 0; ld < 30; ++ld) {
        const int flat = (wid * 30 + ld) * 64 + lane;
        const int st   = flat / 96;            // magic-mul, init-time only
        doff[ld] = st * ROWF + (flat - st * 96);
    }

    auto stage_blk = [&](int b) {
        const float* xblk = xphy + (size_t)b * (BLK * ROWF) + g0 * 3;
        float* lb0 = &s_stage[(b % 3) * SLOT];
        #pragma unroll
        for (int ld = 0; ld < 30; ++ld) {
            __builtin_amdgcn_global_load_lds((gptr_t)(xblk + doff[ld]),
                (lptr_t)(lb0 + (wid * 30 + ld) * 64), 4, 0, 0);
        }
    };

#define SNOWSTEP(P_, T_, ttp_, cfmax_, cfrcf_, cwh_, sp_, mw_, RT_) do {    \
    const float dT_   = (T_) - (ttp_);                                      \
    const float rain_ = ((T_) >= (ttp_)) ? (P_) : 0.0f;                     \
    const float snw_  = (P_) - rain_;                                       \
    const float mc_   = (cfmax_) * fmaxf(dT_, 0.0f);                        \
    const float rc_   = (cfrcf_) * fmaxf(-dT_, 0.0f);                       \
    (sp_) += snw_;                                                          \
    const float melt_ = fminf(mc_, (sp_));                                  \
    (mw_) += melt_;                                                         \
    (sp_) -= melt_;                                                         \
    const float rf_ = fminf(rc_, (mw_));                                    \
    (mw_) -= rf_;                                                           \
    (sp_) += rf_;                                                           \
    const float ts_ = fmaxf(fmaf(-(cwh_), (sp_), (mw_)), 0.0f);             \
    (mw_) -= ts_;                                                           \
    (RT_) = rain_ + ts_;                                                    \
} while (0)

#define SOILSTEP(RT_, EV_, beta_, blfc_, fc_, rlpfc_, sm_, REX_) do {       \
    const float sw_  = __builtin_amdgcn_exp2f(fmaf((beta_),                 \
                         __builtin_amdgcn_logf((sm_)), (blfc_)));           \
    const float sp_  = (sm_) + (RT_);                                       \
    const float sm1_ = fmaf(-(RT_), sw_, sp_);                              \
    const float sm2_ = fminf(sm1_, (fc_));                                  \
    const float uf_  = fmaxf(fmaf(-(EV_), (rlpfc_), 1.0f), 0.0f);           \
    (sm_) = fmaxf(fmaxf(sm2_ * uf_, sm2_ - (EV_)), 1e-5f);                  \
    (REX_) = fmaf((RT_), sw_, sm1_ - sm2_);                                 \
} while (0)

#define RESPSTEP(REX_, perc_, uzl_, k0_, k1_, k2_, o1_, o2_, suz_, slz_, Q_) do { \
    const float s1_ = (suz_) + (REX_);                                      \
    const float pc_ = fminf(s1_, (perc_));                                  \
    const float sA_ = s1_ - pc_;                                            \
    const float tq_ = fmaxf(sA_ - (uzl_), 0.0f);                            \
    const float q0_ = (k0_) * tq_;                                          \
    const float sB_ = fmaf(-(k0_), tq_, sA_);                               \
    const float q1_ = (k1_) * sB_;                                          \
    (suz_) = sB_ * (o1_);                                                   \
    const float sl_ = (slz_) + pc_;                                         \
    const float q2_ = (k2_) * sl_;                                          \
    (slz_) = sl_ * (o2_);                                                   \
    (Q_) = q0_ + q1_ + q2_;                                                 \
} while (0)

    if (wid < 2) {
        stage_blk(0);
        asm volatile("s_waitcnt vmcnt(0)" ::: "memory");
    }
    WG_BARRIER();

    for (int i = 0; i <= NBLK + 1; ++i) {   // 0..51
        if (wid == 0) {
            if (i + 1 < NBLK) stage_blk(i + 1);
            if (i < NBLK) {
                const float* sb = &s_stage[(i % 3) * SLOT];
                f32x2* rtw = &s_rt[(i & 1) * (PAIRS * 128)];
                float reA = 0.0f, reB = 0.0f;
                #pragma unroll
                for (int j = 0; j < BLK; ++j) {
                    const float PA = sb[j * STW + cellA * 3];
                    const float TA = sb[j * STW + cellA * 3 + 1];
                    const float PB = sb[j * STW + cellB * 3];
                    const float TB = sb[j * STW + cellB * 3 + 1];
                    float rtA, rtB;
                    SNOWSTEP(PA, TA, ttpA, cfmaxA, cfrcfA, cwhA, spA, mwA, rtA);
                    SNOWSTEP(PB, TB, ttpB, cfmaxB, cfrcfB, cwhB, spB, mwB, rtB);
                    if ((j & 1) == 0) { reA = rtA; reB = rtB; }
                    else {
                        f32x2 a; a[0] = reA; a[1] = rtA; rtw[(j >> 1) * 128 + lane] = a;
                        f32x2 b; b[0] = reB; b[1] = rtB; rtw[(j >> 1) * 128 + 64 + lane] = b;
                    }
                }
            }
            asm volatile("s_waitcnt vmcnt(0)" ::: "memory");
        } else if (wid == 1) {
            if (i + 1 < NBLK) stage_blk(i + 1);
            const int b = i - 1;
            if (b >= 0 && b < NBLK) {
                const float* sbe = &s_stage[(b % 3) * SLOT];
                const f32x2* rtr = &s_rt[(b & 1) * (PAIRS * 128)];
                f32x2* rexw = &s_rex[(b & 1) * (PAIRS * 128)];
                f32x2 rpA, rpB;
                rpA[0] = 0.0f; rpA[1] = 0.0f; rpB = rpA;
                float xeA = 0.0f, xeB = 0.0f;
                #pragma unroll
                for (int j = 0; j < BLK; ++j) {
                    if ((j & 1) == 0) {
                        rpA = rtr[(j >> 1) * 128 + lane];
                        rpB = rtr[(j >> 1) * 128 + 64 + lane];
                    }
                    const float rtA = ((j & 1) == 0) ? rpA[0] : rpA[1];
                    const float rtB = ((j & 1) == 0) ? rpB[0] : rpB[1];
                    const float evA = sbe[j * STW + cellA * 3 + 2];
                    const float evB = sbe[j * STW + cellB * 3 + 2];
                    float rxA, rxB;
                    SOILSTEP(rtA, evA, betaA, blfcA, fcA, rlpfcA, smA, rxA);
                    SOILSTEP(rtB, evB, betaB, blfcB, fcB, rlpfcB, smB, rxB);
                    if ((j & 1) == 0) { xeA = rxA; xeB = rxB; }
                    else {
                        f32x2 a; a[0] = xeA; a[1] = rxA; rexw[(j >> 1) * 128 + lane] = a;
                        f32x2 b2; b2[0] = xeB; b2[1] = rxB; rexw[(j >> 1) * 128 + 64 + lane] = b2;
                    }
                }
            }
            asm volatile("s_waitcnt vmcnt(0)" ::: "memory");
        } else {
            const int b = i - 2;
            if (b >= 0 && b < NBLK) {
                const int t0 = b * BLK;
                const f32x2* rexr = &s_rex[(b & 1) * (PAIRS * 128)];
                f32x2 rpA, rpB;
                rpA[0] = 0.0f; rpA[1] = 0.0f; rpB = rpA;
                float ovA[BLK / 4], ovB[BLK / 4];
                #pragma unroll
                for (int k = 0; k < BLK / 4; ++k) { ovA[k] = 0.0f; ovB[k] = 0.0f; }
                #pragma unroll
                for (int j = 0; j < BLK; ++j) {
                    if ((j & 1) == 0) {
                        rpA = rexr[(j >> 1) * 128 + lane];
                        rpB = rexr[(j >> 1) * 128 + 64 + lane];
                    }
                    const float rxA = ((j & 1) == 0) ? rpA[0] : rpA[1];
                    const float rxB = ((j & 1) == 0) ? rpB[0] : rpB[1];
                    float qA, qB;
                    RESPSTEP(rxA, percA, uzlA, k0A, k1A, k2A, onemk1A, onemk2A, suzA, slzA, qA);
                    RESPSTEP(rxB, percB, uzlB, k0B, k1B, k2B, onemk1B, onemk2B, suzB, slzB, qB);
                    qA = quad_sum(qA);
                    qB = quad_sum(qB);
                    const bool sel = ((j & 3) == m);
                    ovA[j >> 2] = sel ? qA : ovA[j >> 2];   // j>>2 compile-time
                    ovB[j >> 2] = sel ? qB : ovB[j >> 2];
                }
                #pragma unroll
                for (int k = 0; k < BLK / 4; ++k) {
                    const int t = t0 + k * 4 + m;           // always < TT (exact fit)
                    qm[(size_t)t * NG + gA] = ovA[k];
                    qm[(size_t)t * NG + gB] = ovB[k];
                }
            }
            // no stage loads, no vmcnt drain: stores ride across the barrier
        }
        WG_BARRIER();
    }
}

// Kernel 2: 15-tap routing conv — embarrassingly parallel over (t, g),
// memory-bound (proven r17). w from compile-time log2(k+0.5) constants;
// gammaln/th^aa cancel under normalization; 0.25 multiplier-mean folded.
__global__ __launch_bounds__(256) void hbv_conv_kernel(
    const float* __restrict__ qm,     // [T, G] quad-sums
    const float* __restrict__ prm,    // [1, G, 50]
    float* __restrict__ out)          // [T-WARM, G]
{
    const int g = blockIdx.x * 256 + threadIdx.x;
    if (g >= NG) return;
    const int t0 = WARM + blockIdx.y * 8;

    const float* pr = prm + (size_t)g * 50;
    const float aa  = fmaxf(pr[48] * 2.9f, 0.0f) + 0.1f;
    const float th  = fmaxf(pr[49] * 6.5f, 0.0f) + 0.5f;
    const float aam1 = aa - 1.0f;
    const float rthl = 1.4426950408889634f / th;

    const float L2TG[LENF] = {
        -1.0f, 0.5849625007211562f, 1.3219280948873623f, 1.8073549220576042f,
        2.169925001442312f, 2.4594316186372973f, 2.700439718141092f,
        2.9068905956085187f, 3.087462841250339f, 3.247927513443585f,
        3.3923174227787602f, 3.523561956057013f, 3.643856189774724f,
        3.754887502163468f, 3.857980995127572f };

    float w[LENF];
    float wsum = 0.0f;
    #pragma unroll
    for (int k = 0; k < LENF; ++k) {
        const float tg = (float)k + 0.5f;
        w[k] = __builtin_amdgcn_exp2f(fmaf(aam1, L2TG[k], -tg * rthl));
        wsum += w[k];
    }
    const float rw = 0.25f / wsum;   // 0.25 = mean over the 4 multipliers

    float qv[22];
    #pragma unroll
    for (int j = 0; j < 22; ++j) {
        int t = t0 - 14 + j; t = (t < TT) ? t : (TT - 1);
        qv[j] = qm[(size_t)t * NG + g];
    }
    #pragma unroll
    for (int c = 0; c < 8; ++c) {
        float o = 0.0f;
        #pragma unroll
        for (int k = 0; k < LENF; ++k)
            o = fmaf(w[k], qv[14 + c - k], o);
        const int t = t0 + c;
        if (t < TT) out[(size_t)(t - WARM) * NG + g] = o * rw;
    }
}

extern "C" void kernel_launch(void* const* d_in, const int* in_sizes, int n_in,
                              void* d_out, int out_size, void* d_ws, size_t ws_size,
                              hipStream_t stream) {
    const float* xphy = (const float*)d_in[0];   // [2000, 4000, 3]
    const float* prm  = (const float*)d_in[1];   // [1, 4000, 50]
    float* out = (float*)d_out;                  // [1635, 4000, 1]
    float* qm  = (float*)d_ws;                   // [2000, 4000] = 32 MB

    hbv_chain_kernel<<<NG / 32, 192, 0, stream>>>(xphy, prm, qm);

    dim3 grid2((NG + 255) / 256, (TT - WARM + 7) / 8);   // 16 x 205
    hbv_conv_kernel<<<grid2, 256, 0, stream>>>(qm, prm, out);
}

// Round 19
// 146.697 us; speedup vs baseline: 1.5111x; 1.5111x over previous
//
#include <hip/hip_runtime.h>

#define TT    2000
#define NG    4000
#define WARM  365
#define LENF  15
#define NPHY  12
#define BLK   60                  // timesteps per staged block
#define NBLK  34                  // 34*60 = 2040 steps (covers TT, stores gated)
#define SLOTW 64                  // dwords per step in stage slot (48 used + pad)
#define SLOT  (BLK * SLOTW)       // 3840 floats per stage slot
#define ROWF  (3 * NG)            // floats per timestep row

typedef const float __attribute__((address_space(1)))* gptr_t;
typedef float __attribute__((address_space(3)))* lptr_t;
typedef __attribute__((ext_vector_type(4))) float f32x4;

// Quad-wide sum via DPP (VALU-only). All 4 lanes of a quad get the sum.
__device__ __forceinline__ float quad_sum(float x) {
    int a = __builtin_amdgcn_update_dpp(0, __float_as_int(x), 0xB1, 0xF, 0xF, true);
    float s = x + __int_as_float(a);
    int b = __builtin_amdgcn_update_dpp(0, __float_as_int(s), 0x4E, 0xF, 0xF, true);
    return s + __int_as_float(b);
}

#define WG_BARRIER() asm volatile("s_waitcnt lgkmcnt(0)\n\ts_barrier" ::: "memory")

// r19 = r14 (best, 127us) with the critical soil wave slimmed:
//   wave0: stage-share + snow chain + pack (rt, ev) -> s_rtev ring (b128)
//   wave1: SOIL ONLY: read (rt,ev) quads, 10-op chain, rex b128 quads out
//   wave2: response chain + quad mean -> s_q ring (b128 quads)
//   wave3: stage-share + 15-tap conv + out stores (r14-proven code)
// Ring DS ops halved (b128, 2-4 steps/op); wave1 no longer reads the stage
// buffer -> stage ring is 2-deep; everything else is the r14 discipline.
__global__ __launch_bounds__(256, 1) void hbv_pipe_kernel(
    const float* __restrict__ xphy,   // [T, G, 3]
    const float* __restrict__ prm,    // [1, G, 50]
    float* __restrict__ out)          // [T-WARM, G]
{
    __shared__ float s_stage[2 * SLOT];         // 30720 B, 2-slot ring
    __shared__ f32x4 s_rtev[2 * (BLK / 2) * 64]; // {rt0,ev0,rt1,ev1}  61440 B
    __shared__ f32x4 s_rex [2 * (BLK / 4) * 64]; // {rex0..3}          30720 B
    __shared__ f32x4 s_q   [2 * (BLK / 4) * 64]; // {q0..3}            30720 B

    const int lane = threadIdx.x & 63;
    const int wid  = threadIdx.x >> 6;    // 0..3
    const int g0   = blockIdx.x * 16;     // 250 WGs * 16 cells
    const int cell = lane >> 2;
    const int g    = g0 + cell;
    const int m    = lane & 3;

    const float* pg = prm + (size_t)g * (NPHY * 4 + 2);

    const float lb[NPHY] = {1.0f, 50.0f, 0.05f, 0.01f, 0.001f, 0.2f, 0.0f, 0.0f, -2.5f, 0.5f, 0.0f, 0.0f};
    const float ub[NPHY] = {6.0f, 1000.0f, 0.9f, 0.5f, 0.2f, 1.0f, 10.0f, 100.0f, 2.5f, 10.0f, 0.1f, 0.2f};
    float ph[NPHY];
    #pragma unroll
    for (int i = 0; i < NPHY; ++i)
        ph[i] = lb[i] + pg[i * 4 + m] * (ub[i] - lb[i]);

    const float beta = ph[0], fc = ph[1], k0 = ph[2], k1 = ph[3], k2 = ph[4],
                lp = ph[5], perc = ph[6], uzl = ph[7], ttp = ph[8],
                cfmax = ph[9], cfr = ph[10], cwh = ph[11];
    const float rlpfc  = 1.0f / (lp * fc);
    const float cfrcf  = cfr * cfmax;
    const float blfc   = beta * __builtin_amdgcn_logf(1.0f / fc);
    const float onemk1 = 1.0f - k1;
    const float onemk2 = 1.0f - k2;

    // Routing weights (gammaln / th^aa cancel under normalization); 0.25 folded.
    const float aa  = fmaxf(pg[48] * 2.9f, 0.0f) + 0.1f;
    const float th  = fmaxf(pg[49] * 6.5f, 0.0f) + 0.5f;
    const float rth = 1.0f / th;
    const float LOG2E = 1.4426950408889634f;
    float w[LENF];
    float wsum = 0.0f;
    #pragma unroll
    for (int k = 0; k < LENF; ++k) {
        const float tg = (float)k + 0.5f;
        const float e = (aa - 1.0f) * __builtin_log2f(tg) - tg * rth * LOG2E;
        w[k] = __builtin_amdgcn_exp2f(e);
        wsum += w[k];
    }
    const float rw = 0.25f / wsum;
    #pragma unroll
    for (int k = 0; k < LENF; ++k) w[k] *= rw;

    // Per-wave persistent states
    float snowpack = 0.001f, meltwater = 0.001f;   // wave0
    float sm = 0.001f;                             // wave1
    float suz = 0.001f, slz = 0.001f;              // wave2
    float qh[BLK + LENF - 1];                      // wave3: q history (static idx)
    #pragma unroll
    for (int d = 0; d < BLK + LENF - 1; ++d) qh[d] = 0.0f;

    const int loffd = (lane < 48 ? lane : 47);

    // distributed staging: each of the 4 waves loads 15 steps of block b
    auto stage_blk = [&](int b) {
        const int tb = b * BLK + wid * 15;
        float* ldst = &s_stage[(b & 1) * SLOT + (wid * 15) * SLOTW];
        #pragma unroll
        for (int c = 0; c < 15; ++c) {
            int t = tb + c; t = (t < TT) ? t : (TT - 1);
            const float* src = xphy + (size_t)t * ROWF + g0 * 3 + loffd;
            __builtin_amdgcn_global_load_lds((gptr_t)src, (lptr_t)(ldst + c * SLOTW), 4, 0, 0);
        }
    };

    stage_blk(0);
    asm volatile("s_waitcnt vmcnt(0)" ::: "memory");
    WG_BARRIER();

    for (int i = 0; i <= NBLK + 2; ++i) {
        if (i + 1 < NBLK) stage_blk(i + 1);   // lands by end-of-iter drain

        if (wid == 0) {
            // ---- snow chain + (rt, ev) packing, block i ----
            if (i < NBLK) {
                const float* sb = &s_stage[(i & 1) * SLOT + cell * 3];
                f32x4* rtw = &s_rtev[(i & 1) * ((BLK / 2) * 64) + lane];
                float rtE = 0.0f, evE = 0.0f;
                #pragma unroll
                for (int j = 0; j < BLK; ++j) {
                    const float Pt = sb[j * SLOTW];
                    const float Tm = sb[j * SLOTW + 1];
                    const float ev = sb[j * SLOTW + 2];
                    const float dT      = Tm - ttp;
                    const float rain    = (Tm >= ttp) ? Pt : 0.0f;
                    const float snw     = Pt - rain;
                    const float meltcap = cfmax * fmaxf(dT, 0.0f);
                    const float refcap  = cfrcf * fmaxf(-dT, 0.0f);
                    snowpack += snw;
                    const float melt = fminf(meltcap, snowpack);
                    meltwater += melt;
                    snowpack  -= melt;
                    const float refreeze = fminf(refcap, meltwater);
                    meltwater -= refreeze;
                    snowpack  += refreeze;
                    const float tosoil = fmaxf(fmaf(-cwh, snowpack, meltwater), 0.0f);
                    meltwater -= tosoil;
                    const float rt = rain + tosoil;
                    if ((j & 1) == 0) { rtE = rt; evE = ev; }
                    else {
                        f32x4 q; q[0] = rtE; q[1] = evE; q[2] = rt; q[3] = ev;
                        rtw[(j >> 1) * 64] = q;
                    }
                }
            }
            asm volatile("s_waitcnt vmcnt(0)" ::: "memory");
        } else if (wid == 1) {
            // ---- soil chain ONLY, block i-1 (critical wave, slimmed) ----
            const int b = i - 1;
            if (b >= 0 && b < NBLK) {
                const f32x4* rtr = &s_rtev[(b & 1) * ((BLK / 2) * 64) + lane];
                f32x4* rexw = &s_rex[(b & 1) * ((BLK / 4) * 64) + lane];
                f32x4 rp; rp[0] = 0.0f; rp[1] = 0.0f; rp[2] = 0.0f; rp[3] = 0.0f;
                float x0 = 0.0f, x1 = 0.0f, x2 = 0.0f;
                #pragma unroll
                for (int j = 0; j < BLK; ++j) {
                    if ((j & 1) == 0) rp = rtr[(j >> 1) * 64];
                    const float rt = ((j & 1) == 0) ? rp[0] : rp[2];
                    const float ev = ((j & 1) == 0) ? rp[1] : rp[3];
                    const float sw  = __builtin_amdgcn_exp2f(fmaf(beta, __builtin_amdgcn_logf(sm), blfc));
                    const float sp  = sm + rt;
                    const float sm1 = fmaf(-rt, sw, sp);
                    const float sm2 = fminf(sm1, fc);
                    const float uf  = fmaxf(fmaf(-ev, rlpfc, 1.0f), 0.0f);
                    sm = fmaxf(fmaxf(sm2 * uf, sm2 - ev), 1e-5f);   // v_max3
                    const float rex = fmaf(rt, sw, sm1 - sm2);
                    if ((j & 3) == 0)      x0 = rex;
                    else if ((j & 3) == 1) x1 = rex;
                    else if ((j & 3) == 2) x2 = rex;
                    else {
                        f32x4 q; q[0] = x0; q[1] = x1; q[2] = x2; q[3] = rex;
                        rexw[(j >> 2) * 64] = q;
                    }
                }
            }
            asm volatile("s_waitcnt vmcnt(0)" ::: "memory");
        } else if (wid == 2) {
            // ---- response chain + quad mean, block i-2 ----
            const int b = i - 2;
            if (b >= 0 && b < NBLK) {
                const f32x4* rexr = &s_rex[(b & 1) * ((BLK / 4) * 64) + lane];
                f32x4* qw = &s_q[(b & 1) * ((BLK / 4) * 64) + lane];
                f32x4 rp; rp[0] = 0.0f; rp[1] = 0.0f; rp[2] = 0.0f; rp[3] = 0.0f;
                float q0v = 0.0f, q1v = 0.0f, q2v = 0.0f;
                #pragma unroll
                for (int j = 0; j < BLK; ++j) {
                    if ((j & 3) == 0) rp = rexr[(j >> 2) * 64];
                    const float rex = ((j & 3) == 0) ? rp[0] : ((j & 3) == 1) ? rp[1]
                                     : ((j & 3) == 2) ? rp[2] : rp[3];
                    const float suz1 = suz + rex;
                    const float prc  = fminf(suz1, perc);
                    const float suzA = suz1 - prc;
                    const float tq   = fmaxf(suzA - uzl, 0.0f);
                    const float q0   = k0 * tq;
                    const float suzB = fmaf(-k0, tq, suzA);
                    const float q1   = k1 * suzB;
                    suz = suzB * onemk1;
                    const float sl1  = slz + prc;
                    const float q2   = k2 * sl1;
                    slz = sl1 * onemk2;
                    const float q = quad_sum(q0 + q1 + q2);   // *0.25 folded in w
                    if ((j & 3) == 0)      q0v = q;
                    else if ((j & 3) == 1) q1v = q;
                    else if ((j & 3) == 2) q2v = q;
                    else {
                        f32x4 qq; qq[0] = q0v; qq[1] = q1v; qq[2] = q2v; qq[3] = q;
                        qw[(j >> 2) * 64] = qq;
                    }
                }
            }
            asm volatile("s_waitcnt vmcnt(0)" ::: "memory");
        } else {
            // ---- 15-tap conv (gather form) + stores, block i-3 ----
            const int b = i - 3;
            if (b >= 0 && b < NBLK) {
                const int t0 = b * BLK;
                const f32x4* qr = &s_q[(b & 1) * ((BLK / 4) * 64) + lane];
                #pragma unroll
                for (int p = 0; p < BLK / 4; ++p) {
                    const f32x4 qq = qr[p * 64];
                    qh[LENF - 1 + 4 * p]     = qq[0];
                    qh[LENF - 1 + 4 * p + 1] = qq[1];
                    qh[LENF - 1 + 4 * p + 2] = qq[2];
                    qh[LENF - 1 + 4 * p + 3] = qq[3];
                }
                float ov[BLK / 4];
                #pragma unroll
                for (int k = 0; k < BLK / 4; ++k) ov[k] = 0.0f;
                #pragma unroll
                for (int j = 0; j < BLK; ++j) {
                    float o = w[0] * qh[LENF - 1 + j];
                    #pragma unroll
                    for (int k = 1; k < LENF; ++k)
                        o = fmaf(w[k], qh[LENF - 1 + j - k], o);
                    const bool sel = ((j & 3) == m);
                    ov[j >> 2] = sel ? o : ov[j >> 2];     // j>>2 compile-time
                }
                #pragma unroll
                for (int d = 0; d < LENF - 1; ++d) qh[d] = qh[d + BLK];   // static shift
                #pragma unroll
                for (int k = 0; k < BLK / 4; ++k) {
                    const int j = k * 4 + m;
                    const int t = t0 + j;
                    if (t >= WARM && t < TT)
                        out[(size_t)(t - WARM) * NG + g] = ov[k];
                }
            }
            asm volatile("s_waitcnt vmcnt(0)" ::: "memory");
        }

        WG_BARRIER();
    }
}

extern "C" void kernel_launch(void* const* d_in, const int* in_sizes, int n_in,
                              void* d_out, int out_size, void* d_ws, size_t ws_size,
                              hipStream_t stream) {
    const float* xphy = (const float*)d_in[0];   // [2000, 4000, 3]
    const float* prm  = (const float*)d_in[1];   // [1, 4000, 50]
    float* out = (float*)d_out;                  // [1635, 4000, 1]

    hbv_pipe_kernel<<<NG / 16, 256, 0, stream>>>(xphy, prm, out);
}

// Round 20
// 134.783 us; speedup vs baseline: 1.6446x; 1.0884x over previous
//
#include <hip/hip_runtime.h>

#define TT    2000
#define NG    4000
#define WARM  365
#define LENF  15
#define NPHY  12
#define BLK   60                  // timesteps per staged block
#define NBLK  34                  // 34*60 = 2040 steps (covers TT, stores gated)
#define SLOTW 64                  // dwords per step: 16 cells x 4 (P,T,ev,pad)
#define SLOT  (BLK * SLOTW)       // 3840 dwords per stage slot
#define ROWF  (3 * NG)            // floats per timestep row

typedef const float __attribute__((address_space(1)))* gptr_t;
typedef float __attribute__((address_space(3)))* lptr_t;
typedef __attribute__((ext_vector_type(2))) float f32x2;
typedef __attribute__((ext_vector_type(4))) float f32x4;

// Quad-wide sum via DPP (VALU-only). All 4 lanes of a quad get the sum.
__device__ __forceinline__ float quad_sum(float x) {
    int a = __builtin_amdgcn_update_dpp(0, __float_as_int(x), 0xB1, 0xF, 0xF, true);
    float s = x + __int_as_float(a);
    int b = __builtin_amdgcn_update_dpp(0, __float_as_int(s), 0x4E, 0xF, 0xF, true);
    return s + __int_as_float(b);
}

#define WG_BARRIER() asm volatile("s_waitcnt lgkmcnt(0)\n\ts_barrier" ::: "memory")

// r20 = r14 (best, 127us) with wave0 (the measured critical wave) slimmed:
//   - stage layout = aligned 16B quads per cell: ONE size-16 global_load_lds
//     stages 4 steps x 16 cells -> 15 loads/block, ALL issued by wave3.
//   - wave0: 1 ds_read_b128/step (P,T,ev,pad), snow chain, {rt,ev} packed
//     f32x4 ring write per 2 steps (same op count as r14's b64).
//   - wave1: 0.5 ds_read_b128/step (rt+ev from ring; no stage access),
//     soil chain, rex b64 pairs out (r14 form).
//   - wave2/wave3 compute bodies = r14 exactly.
//   - stage ring 2-deep (only wave0 reads it); only wave3 drains vmcnt.
__global__ __launch_bounds__(256, 1) void hbv_pipe_kernel(
    const float* __restrict__ xphy,   // [T, G, 3]
    const float* __restrict__ prm,    // [1, G, 50]
    float* __restrict__ out)          // [T-WARM, G]
{
    __shared__ float s_stage[2 * SLOT];          // 30720 B, 2-slot ring
    __shared__ f32x4 s_rtev[2 * (BLK / 2) * 64]; // {rtE,evE,rtO,evO} 61440 B
    __shared__ f32x2 s_rex [2 * (BLK / 2) * 64]; // rex pairs         30720 B
    __shared__ f32x2 s_q   [2 * (BLK / 2) * 64]; // q pairs           30720 B

    const int lane = threadIdx.x & 63;
    const int wid  = threadIdx.x >> 6;    // 0..3
    const int g0   = blockIdx.x * 16;     // 250 WGs * 16 cells
    const int cell = lane >> 2;
    const int g    = g0 + cell;
    const int m    = lane & 3;

    const float* pg = prm + (size_t)g * (NPHY * 4 + 2);

    const float lb[NPHY] = {1.0f, 50.0f, 0.05f, 0.01f, 0.001f, 0.2f, 0.0f, 0.0f, -2.5f, 0.5f, 0.0f, 0.0f};
    const float ub[NPHY] = {6.0f, 1000.0f, 0.9f, 0.5f, 0.2f, 1.0f, 10.0f, 100.0f, 2.5f, 10.0f, 0.1f, 0.2f};
    float ph[NPHY];
    #pragma unroll
    for (int i = 0; i < NPHY; ++i)
        ph[i] = lb[i] + pg[i * 4 + m] * (ub[i] - lb[i]);

    const float beta = ph[0], fc = ph[1], k0 = ph[2], k1 = ph[3], k2 = ph[4],
                lp = ph[5], perc = ph[6], uzl = ph[7], ttp = ph[8],
                cfmax = ph[9], cfr = ph[10], cwh = ph[11];
    const float rlpfc  = 1.0f / (lp * fc);
    const float cfrcf  = cfr * cfmax;
    const float blfc   = beta * __builtin_amdgcn_logf(1.0f / fc);
    const float onemk1 = 1.0f - k1;
    const float onemk2 = 1.0f - k2;

    // Routing weights (gammaln / th^aa cancel under normalization); 0.25 folded.
    const float aa  = fmaxf(pg[48] * 2.9f, 0.0f) + 0.1f;
    const float th  = fmaxf(pg[49] * 6.5f, 0.0f) + 0.5f;
    const float rth = 1.0f / th;
    const float LOG2E = 1.4426950408889634f;
    float w[LENF];
    float wsum = 0.0f;
    #pragma unroll
    for (int k = 0; k < LENF; ++k) {
        const float tg = (float)k + 0.5f;
        const float e = (aa - 1.0f) * __builtin_log2f(tg) - tg * rth * LOG2E;
        w[k] = __builtin_amdgcn_exp2f(e);
        wsum += w[k];
    }
    const float rw = 0.25f / wsum;
    #pragma unroll
    for (int k = 0; k < LENF; ++k) w[k] *= rw;

    // Per-wave persistent states
    float snowpack = 0.001f, meltwater = 0.001f;   // wave0
    float sm = 0.001f;                             // wave1
    float suz = 0.001f, slz = 0.001f;              // wave2
    float qh[BLK + LENF - 1];                      // wave3: q history (static idx)
    #pragma unroll
    for (int d = 0; d < BLK + LENF - 1; ++d) qh[d] = 0.0f;

    // size-16 staging geometry (wave3 only): lane = s*16 + c covers substep s
    // (0..3) of cell c; one load = 4 steps x 16 cells = 64 x 16B.
    const int s4 = lane >> 4;          // 0..3 substep
    const int c4 = lane & 15;          // cell

    auto stage_blk = [&](int b) {      // 15 loads per 60-step block
        float* lbase = &s_stage[(b & 1) * SLOT];
        #pragma unroll
        for (int ld = 0; ld < 15; ++ld) {
            int t = b * BLK + ld * 4 + s4;
            t = (t < TT) ? t : (TT - 1);                  // tail clamp
            const float* src = xphy + (size_t)t * ROWF + (g0 + c4) * 3;
            __builtin_amdgcn_global_load_lds((gptr_t)src,
                (lptr_t)(lbase + ld * 4 * SLOTW), 16, 0, 0);
        }
    };

    if (wid == 3) {
        stage_blk(0);
        asm volatile("s_waitcnt vmcnt(0)" ::: "memory");
    }
    WG_BARRIER();

    for (int i = 0; i <= NBLK + 2; ++i) {
        if (wid == 0) {
            // ---- snow chain, block i: 1 b128 read/step, pack {rt,ev} ----
            if (i < NBLK) {
                const f32x4* sb = (const f32x4*)&s_stage[(i & 1) * SLOT + cell * 4];
                f32x4* rtw = &s_rtev[(i & 1) * ((BLK / 2) * 64) + lane];
                float rtE = 0.0f, evE = 0.0f;
                #pragma unroll
                for (int j = 0; j < BLK; ++j) {
                    const f32x4 x = sb[j * 16];           // {P, T, ev, pad}
                    const float Pt = x[0], Tm = x[1], ev = x[2];
                    const float dT      = Tm - ttp;
                    const float rain    = (Tm >= ttp) ? Pt : 0.0f;
                    const float snw     = Pt - rain;
                    const float meltcap = cfmax * fmaxf(dT, 0.0f);
                    const float refcap  = cfrcf * fmaxf(-dT, 0.0f);
                    snowpack += snw;
                    const float melt = fminf(meltcap, snowpack);
                    meltwater += melt;
                    snowpack  -= melt;
                    const float refreeze = fminf(refcap, meltwater);
                    meltwater -= refreeze;
                    snowpack  += refreeze;
                    const float tosoil = fmaxf(fmaf(-cwh, snowpack, meltwater), 0.0f);
                    meltwater -= tosoil;
                    const float rt = rain + tosoil;
                    if ((j & 1) == 0) { rtE = rt; evE = ev; }
                    else {
                        f32x4 q; q[0] = rtE; q[1] = evE; q[2] = rt; q[3] = ev;
                        rtw[(j >> 1) * 64] = q;
                    }
                }
            }
        } else if (wid == 1) {
            // ---- soil chain, block i-1: rt+ev from ring, no stage access ----
            const int b = i - 1;
            if (b >= 0 && b < NBLK) {
                const f32x4* rtr = &s_rtev[(b & 1) * ((BLK / 2) * 64) + lane];
                f32x2* rexw = &s_rex[(b & 1) * ((BLK / 2) * 64) + lane];
                f32x4 rp; rp[0] = 0.0f; rp[1] = 0.0f; rp[2] = 0.0f; rp[3] = 0.0f;
                float rexE = 0.0f;
                #pragma unroll
                for (int j = 0; j < BLK; ++j) {
                    if ((j & 1) == 0) rp = rtr[(j >> 1) * 64];
                    const float rt = ((j & 1) == 0) ? rp[0] : rp[2];
                    const float ev = ((j & 1) == 0) ? rp[1] : rp[3];
                    const float sw  = __builtin_amdgcn_exp2f(fmaf(beta, __builtin_amdgcn_logf(sm), blfc));
                    const float sp  = sm + rt;
                    const float sm1 = fmaf(-rt, sw, sp);
                    const float sm2 = fminf(sm1, fc);
                    const float uf  = fmaxf(fmaf(-ev, rlpfc, 1.0f), 0.0f);
                    sm = fmaxf(fmaxf(sm2 * uf, sm2 - ev), 1e-5f);   // v_max3
                    const float rex = fmaf(rt, sw, sm1 - sm2);
                    if ((j & 1) == 0) rexE = rex;
                    else { f32x2 pr; pr[0] = rexE; pr[1] = rex; rexw[(j >> 1) * 64] = pr; }
                }
            }
        } else if (wid == 2) {
            // ---- response chain + quad mean, block i-2 (r14 body) ----
            const int b = i - 2;
            if (b >= 0 && b < NBLK) {
                const f32x2* rexr = &s_rex[(b & 1) * ((BLK / 2) * 64) + lane];
                f32x2* qw = &s_q[(b & 1) * ((BLK / 2) * 64) + lane];
                f32x2 rp; rp[0] = 0.0f; rp[1] = 0.0f;
                float qE = 0.0f;
                #pragma unroll
                for (int j = 0; j < BLK; ++j) {
                    if ((j & 1) == 0) rp = rexr[(j >> 1) * 64];
                    const float rex = ((j & 1) == 0) ? rp[0] : rp[1];
                    const float suz1 = suz + rex;
                    const float prc  = fminf(suz1, perc);
                    const float suzA = suz1 - prc;
                    const float tq   = fmaxf(suzA - uzl, 0.0f);
                    const float q0   = k0 * tq;
                    const float suzB = fmaf(-k0, tq, suzA);
                    const float q1   = k1 * suzB;
                    suz = suzB * onemk1;
                    const float sl1  = slz + prc;
                    const float q2   = k2 * sl1;
                    slz = sl1 * onemk2;
                    const float q = quad_sum(q0 + q1 + q2);   // *0.25 folded in w
                    if ((j & 1) == 0) qE = q;
                    else { f32x2 pr; pr[0] = qE; pr[1] = q; qw[(j >> 1) * 64] = pr; }
                }
            }
        } else {
            // ---- staging + 15-tap conv + stores, block i-3 (r14 body) ----
            if (i + 1 < NBLK) stage_blk(i + 1);
            const int b = i - 3;
            if (b >= 0 && b < NBLK) {
                const int t0 = b * BLK;
                const f32x2* qr = &s_q[(b & 1) * ((BLK / 2) * 64) + lane];
                #pragma unroll
                for (int p = 0; p < BLK / 2; ++p) {
                    const f32x2 qq = qr[p * 64];
                    qh[LENF - 1 + 2 * p]     = qq[0];
                    qh[LENF - 1 + 2 * p + 1] = qq[1];
                }
                float ov[BLK / 4];
                #pragma unroll
                for (int k = 0; k < BLK / 4; ++k) ov[k] = 0.0f;
                #pragma unroll
                for (int j = 0; j < BLK; ++j) {
                    float o = w[0] * qh[LENF - 1 + j];
                    #pragma unroll
                    for (int k = 1; k < LENF; ++k)
                        o = fmaf(w[k], qh[LENF - 1 + j - k], o);
                    const bool sel = ((j & 3) == m);
                    ov[j >> 2] = sel ? o : ov[j >> 2];     // j>>2 compile-time
                }
                #pragma unroll
                for (int d = 0; d < LENF - 1; ++d) qh[d] = qh[d + BLK];   // static shift
                #pragma unroll
                for (int k = 0; k < BLK / 4; ++k) {
                    const int j = k * 4 + m;
                    const int t = t0 + j;
                    if (t >= WARM && t < TT)
                        out[(size_t)(t - WARM) * NG + g] = ov[k];
                }
            }
            // drain staging loads (+ out stores) before the barrier
            asm volatile("s_waitcnt vmcnt(0)" ::: "memory");
        }

        WG_BARRIER();
    }
}

extern "C" void kernel_launch(void* const* d_in, const int* in_sizes, int n_in,
                              void* d_out, int out_size, void* d_ws, size_t ws_size,
                              hipStream_t stream) {
    const float* xphy = (const float*)d_in[0];   // [2000, 4000, 3]
    const float* prm  = (const float*)d_in[1];   // [1, 4000, 50]
    float* out = (float*)d_out;                  // [1635, 4000, 1]

    hbv_pipe_kernel<<<NG / 16, 256, 0, stream>>>(xphy, prm, out);
}

// Round 21
// 126.853 us; speedup vs baseline: 1.7474x; 1.0625x over previous
//
#include <hip/hip_runtime.h>

#define TT    2000
#define NG    4000
#define WARM  365
#define LENF  15
#define NPHY  12
#define BLK   60                  // timesteps per staged block
#define PAIRS (BLK / 2)           // f32x2 pairs per ring slot
#define SLOTW 64                  // dwords per step in stage LDS (48 used + pad)
#define SLOTD (BLK * SLOTW)       // 3840 dwords per stage slot
#define NBLK  34                  // 34*60 = 2040 steps (covers TT, stores gated)
#define ROWF  (3 * NG)            // 12000 floats per timestep row

typedef const float __attribute__((address_space(1)))* gptr_t;
typedef float __attribute__((address_space(3)))* lptr_t;
typedef __attribute__((ext_vector_type(2))) float f32x2;

// Quad-wide sum via DPP (VALU-only; no LDS pipe).
__device__ __forceinline__ float quad_sum(float x) {
    int a = __builtin_amdgcn_update_dpp(0, __float_as_int(x), 0xB1, 0xF, 0xF, true);
    float s = x + __int_as_float(a);
    int b = __builtin_amdgcn_update_dpp(0, __float_as_int(s), 0x4E, 0xF, 0xF, true);
    return s + __int_as_float(b);
}

// Raw barrier: wait own ds ops, then barrier.
#define WG_BARRIER() asm volatile("s_waitcnt lgkmcnt(0)\n\ts_barrier" ::: "memory")

// Wave-specialized pipeline, 4 waves / WG, NC=16 cells (full waves, 250 WGs).
//   wave0: snow chain (block i)        -> s_rt ring (b64 pairs)
//   wave1: soil chain (block i-1)      -> s_rex ring (b64 pairs)
//   wave2: response + quad mean (i-2)  -> s_q ring (b64 pairs)
//   wave3: 15-tap conv + stores (i-3)
// BLK=60 (37 sync events — fixed ~1.4k cyc/iter amortized), staging split
// across ALL 4 waves (15 size-4 global_load_lds each, incremental addresses),
// 3-deep stage ring + per-iter vmcnt(0) drain, b64-paired handoff rings.
// Session optimum (r14 = 126.77us): r15-r20 attacked I-fetch, conv eviction,
// ILP, DS packing — all regressed; structure is latency+sync plateau-bound.
__global__ __launch_bounds__(256, 1) void hbv_pipe_kernel(
    const float* __restrict__ xphy,   // [T, G, 3]
    const float* __restrict__ prm,    // [1, G, 50]
    float* __restrict__ out)          // [T-WARM, G]
{
    __shared__ float s_stage[3 * SLOTD];        // 46080 B input stage ring
    __shared__ f32x2 s_rt [2 * PAIRS * 64];     // snow -> soil     (30720 B)
    __shared__ f32x2 s_rex[2 * PAIRS * 64];     // soil -> response (30720 B)
    __shared__ f32x2 s_q  [2 * PAIRS * 64];     // response -> conv (30720 B)

    const int lane = threadIdx.x & 63;
    const int wid  = threadIdx.x >> 6;    // 0..3
    const int g0   = blockIdx.x * 16;     // 250 workgroups * 16 cells
    const int cell = lane >> 2;
    const int g    = g0 + cell;
    const int m    = lane & 3;

    const float* pg = prm + (size_t)g * (NPHY * 4 + 2);

    const float lb[NPHY] = {1.0f, 50.0f, 0.05f, 0.01f, 0.001f, 0.2f, 0.0f, 0.0f, -2.5f, 0.5f, 0.0f, 0.0f};
    const float ub[NPHY] = {6.0f, 1000.0f, 0.9f, 0.5f, 0.2f, 1.0f, 10.0f, 100.0f, 2.5f, 10.0f, 0.1f, 0.2f};
    float ph[NPHY];
    #pragma unroll
    for (int i = 0; i < NPHY; ++i)
        ph[i] = lb[i] + pg[i * 4 + m] * (ub[i] - lb[i]);

    const float beta = ph[0], fc = ph[1], k0 = ph[2], k1 = ph[3], k2 = ph[4],
                lp = ph[5], perc = ph[6], uzl = ph[7], ttp = ph[8],
                cfmax = ph[9], cfr = ph[10], cwh = ph[11];
    const float rlpfc  = 1.0f / (lp * fc);
    const float cfrcf  = cfr * cfmax;
    const float blfc   = beta * __builtin_amdgcn_logf(1.0f / fc);  // beta*log2(1/fc)
    const float onemk1 = 1.0f - k1;
    const float onemk2 = 1.0f - k2;

    // Routing weights (gammaln / th^aa cancel under normalization); 0.25 folded.
    const float aa  = fmaxf(pg[48] * 2.9f, 0.0f) + 0.1f;
    const float th  = fmaxf(pg[49] * 6.5f, 0.0f) + 0.5f;
    const float rth = 1.0f / th;
    const float LOG2E = 1.4426950408889634f;
    float w[LENF];
    float wsum = 0.0f;
    #pragma unroll
    for (int k = 0; k < LENF; ++k) {
        const float tg = (float)k + 0.5f;
        const float e = (aa - 1.0f) * __builtin_log2f(tg) - tg * rth * LOG2E;
        w[k] = __builtin_amdgcn_exp2f(e);
        wsum += w[k];
    }
    const float rw = 0.25f / wsum;
    #pragma unroll
    for (int k = 0; k < LENF; ++k) w[k] *= rw;

    // Per-wave persistent states
    float snowpack = 0.001f, meltwater = 0.001f;   // wave0
    float sm = 0.001f;                             // wave1
    float suz = 0.001f, slz = 0.001f;              // wave2
    float qh[BLK + LENF - 1];                      // wave3: q history (static idx)
    #pragma unroll
    for (int d = 0; d < BLK + LENF - 1; ++d) qh[d] = 0.0f;

    // ---- distributed staging: each wave loads 15 steps of each block ----
    const int loffd = (lane < 48 ? lane : 47);
    const float* ga = xphy + (size_t)(wid * 15) * ROWF + g0 * 3 + loffd;

    // prologue: block 0 into slot 0
    {
        float* ldst = &s_stage[(wid * 15) * SLOTW];
        #pragma unroll
        for (int cc = 0; cc < 15; ++cc) {
            __builtin_amdgcn_global_load_lds((gptr_t)ga, (lptr_t)(ldst + cc * SLOTW), 4, 0, 0);
            ga += ROWF;
        }
        ga += 45 * ROWF;
    }
    asm volatile("s_waitcnt vmcnt(0)" ::: "memory");
    WG_BARRIER();

    for (int i = 0; i <= NBLK + 2; ++i) {
        // ---- stage block i+1 (all waves, 15 loads each) ----
        if (i < NBLK - 1) {
            const int sl = (i + 1) % 3;
            float* ldst = &s_stage[sl * SLOTD + (wid * 15) * SLOTW];
            if (i + 1 == NBLK - 1) {
                // tail block: clamp t at TT-1
                #pragma unroll
                for (int cc = 0; cc < 15; ++cc) {
                    int t = (NBLK - 1) * BLK + wid * 15 + cc;
                    if (t > TT - 1) t = TT - 1;
                    const float* gsrc = xphy + (size_t)t * ROWF + g0 * 3 + loffd;
                    __builtin_amdgcn_global_load_lds((gptr_t)gsrc, (lptr_t)(ldst + cc * SLOTW), 4, 0, 0);
                }
            } else {
                const float* gp2 = ga;
                #pragma unroll
                for (int cc = 0; cc < 15; ++cc) {
                    __builtin_amdgcn_global_load_lds((gptr_t)gp2, (lptr_t)(ldst + cc * SLOTW), 4, 0, 0);
                    gp2 += ROWF;
                }
                ga = gp2 + 45 * ROWF;
            }
        }

        if (wid == 0) {
            // ---- snow chain, block i ----
            if (i < NBLK) {
                const float* sb = &s_stage[(i % 3) * SLOTD + cell * 3];
                f32x2* rtw = &s_rt[(i & 1) * (PAIRS * 64) + lane];
                float rt_even = 0.0f;
                #pragma unroll
                for (int j = 0; j < BLK; ++j) {
                    const float Pt = sb[j * SLOTW];
                    const float Tm = sb[j * SLOTW + 1];
                    const float dT      = Tm - ttp;
                    const float rain    = (Tm >= ttp) ? Pt : 0.0f;
                    const float snow    = Pt - rain;
                    const float meltcap = cfmax * fmaxf(dT, 0.0f);
                    const float refcap  = cfrcf * fmaxf(-dT, 0.0f);
                    snowpack += snow;
                    const float melt = fminf(meltcap, snowpack);
                    meltwater += melt;
                    snowpack  -= melt;
                    const float refreeze = fminf(refcap, meltwater);
                    meltwater -= refreeze;
                    snowpack  += refreeze;
                    const float tosoil = fmaxf(fmaf(-cwh, snowpack, meltwater), 0.0f);
                    meltwater -= tosoil;
                    const float rt = rain + tosoil;
                    if ((j & 1) == 0) rt_even = rt;
                    else {
                        f32x2 pr; pr[0] = rt_even; pr[1] = rt;
                        rtw[(j >> 1) * 64] = pr;
                    }
                }
            }
        } else if (wid == 1) {
            // ---- soil-moisture chain, block i-1 ----
            const int b = i - 1;
            if (b >= 0 && b < NBLK) {
                const float* sb = &s_stage[(b % 3) * SLOTD + cell * 3 + 2];  // ev
                const f32x2* rtr = &s_rt[(b & 1) * (PAIRS * 64) + lane];
                f32x2* rexw = &s_rex[(b & 1) * (PAIRS * 64) + lane];
                f32x2 prt; prt[0] = 0.0f; prt[1] = 0.0f;
                float rex_even = 0.0f;
                #pragma unroll
                for (int j = 0; j < BLK; ++j) {
                    if ((j & 1) == 0) prt = rtr[(j >> 1) * 64];
                    const float rt = ((j & 1) == 0) ? prt[0] : prt[1];
                    const float ev = sb[j * SLOTW];
                    // sw = (sm/fc)^beta = exp2(beta*log2(sm) + beta*log2(1/fc))
                    const float sw    = __builtin_amdgcn_exp2f(fmaf(beta, __builtin_amdgcn_logf(sm), blfc));
                    const float smprt = sm + rt;
                    const float sm1   = fmaf(-rt, sw, smprt);      // sm + rt*(1-sw)
                    const float sm2   = fminf(sm1, fc);
                    const float uf    = fmaxf(fmaf(-ev, rlpfc, 1.0f), 0.0f);  // 1-evapfac
                    const float av    = sm2 * uf;
                    const float cv    = sm2 - ev;
                    sm = fmaxf(fmaxf(av, cv), 1e-5f);              // v_max3
                    const float rex = fmaf(rt, sw, sm1 - sm2);     // recharge + excess
                    if ((j & 1) == 0) rex_even = rex;
                    else {
                        f32x2 pr; pr[0] = rex_even; pr[1] = rex;
                        rexw[(j >> 1) * 64] = pr;
                    }
                }
            }
        } else if (wid == 2) {
            // ---- response chain + quad mean, block i-2 ----
            const int b = i - 2;
            if (b >= 0 && b < NBLK) {
                const f32x2* rexr = &s_rex[(b & 1) * (PAIRS * 64) + lane];
                f32x2* qw = &s_q[(b & 1) * (PAIRS * 64) + lane];
                f32x2 prx; prx[0] = 0.0f; prx[1] = 0.0f;
                float q_even = 0.0f;
                #pragma unroll
                for (int j = 0; j < BLK; ++j) {
                    if ((j & 1) == 0) prx = rexr[(j >> 1) * 64];
                    const float rex = ((j & 1) == 0) ? prx[0] : prx[1];
                    const float suz1 = suz + rex;
                    const float prc  = fminf(suz1, perc);
                    const float suzA = suz1 - prc;
                    const float tq   = fmaxf(suzA - uzl, 0.0f);
                    const float q0   = k0 * tq;
                    const float suzB = fmaf(-k0, tq, suzA);
                    const float q1   = k1 * suzB;
                    suz = suzB * onemk1;
                    const float slz1 = slz + prc;
                    const float q2   = k2 * slz1;
                    slz = slz1 * onemk2;
                    const float q = quad_sum(q0 + q1 + q2);  // *0.25 folded into w
                    if ((j & 1) == 0) q_even = q;
                    else {
                        f32x2 pr; pr[0] = q_even; pr[1] = q;
                        qw[(j >> 1) * 64] = pr;
                    }
                }
            }
        } else {
            // ---- 15-tap routing conv (gather form) + stores, block i-3 ----
            const int b = i - 3;
            if (b >= 0 && b < NBLK) {
                const int t0 = b * BLK;
                const f32x2* qr = &s_q[(b & 1) * (PAIRS * 64) + lane];
                #pragma unroll
                for (int jp = 0; jp < PAIRS; ++jp) {
                    const f32x2 qp = qr[jp * 64];
                    qh[LENF - 1 + 2 * jp]     = qp[0];
                    qh[LENF - 1 + 2 * jp + 1] = qp[1];
                }
                float ov[BLK / 4];
                #pragma unroll
                for (int k = 0; k < BLK / 4; ++k) ov[k] = 0.0f;
                #pragma unroll
                for (int j = 0; j < BLK; ++j) {
                    float o = w[0] * qh[LENF - 1 + j];
                    #pragma unroll
                    for (int k = 1; k < LENF; ++k)
                        o = fmaf(w[k], qh[LENF - 1 + j - k], o);
                    const bool sel = ((j & 3) == m);
                    ov[j >> 2] = sel ? o : ov[j >> 2];     // j>>2 compile-time
                }
                #pragma unroll
                for (int d = 0; d < LENF - 1; ++d) qh[d] = qh[d + BLK];   // static shift
                #pragma unroll
                for (int k = 0; k < BLK / 4; ++k) {
                    const int j = k * 4 + m;
                    const int t = t0 + j;
                    if (t >= WARM && t < TT)
                        out[(size_t)(t - WARM) * NG + g] = ov[k];
                }
            }
        }

        // own staging loads for block i+1 are ~a full iteration old here
        asm volatile("s_waitcnt vmcnt(0)" ::: "memory");
        WG_BARRIER();
    }
}

extern "C" void kernel_launch(void* const* d_in, const int* in_sizes, int n_in,
                              void* d_out, int out_size, void* d_ws, size_t ws_size,
                              hipStream_t stream) {
    const float* xphy = (const float*)d_in[0];   // [2000, 4000, 3]
    const float* prm  = (const float*)d_in[1];   // [1, 4000, 50]
    float* out = (float*)d_out;                  // [1635, 4000, 1]

    hbv_pipe_kernel<<<NG / 16, 256, 0, stream>>>(xphy, prm, out);
}